// Round 1
// baseline (89.285 us; speedup 1.0000x reference)
//
#include <hip/hip_runtime.h>

#define DEVINL __device__ __forceinline__

DEVINL float rcp_fast(float x) { return __builtin_amdgcn_rcpf(x); }
DEVINL float sigm(float x) { return rcp_fast(1.0f + __expf(-x)); }
DEVINL float tanh_fast(float x) {
    // tanh(x) = 1 - 2/(1 + e^{2x})
    return fmaf(-2.0f, rcp_fast(1.0f + __expf(2.0f * x)), 1.0f);
}

// Broadcast lane L (0..3) of each 4-lane quad to all 4 lanes. DPP quad_perm,
// ctrl = L in all four 2-bit fields = L*0x55. Pure VALU, ~1 cycle.
template <int L>
DEVINL float qbcast(float v) {
    return __int_as_float(__builtin_amdgcn_update_dpp(
        0, __float_as_int(v), L * 0x55, 0xF, 0xF, true));
}

// ---------------------------------------------------------------------------
// Encoder LSTM: T=250, B=250, I=1, H=4. 4 lanes per batch element.
// Lane u owns hidden unit u: gate rows u (i), 4+u (f), 8+u (g), 12+u (o).
// Block = 64 threads = 16 batch elements; grid = 16 blocks.
// Writes y[t,b,u] -> yws[t*1000 + b*4 + u], final c -> cfin[b*4+u].
// ---------------------------------------------------------------------------
__global__ __launch_bounds__(64) void enc_kernel(
    const float* __restrict__ x,       // (250,250) row-major (t,b)
    const float* __restrict__ wih_g,   // (16,1)
    const float* __restrict__ whh_g,   // (16,4)
    const float* __restrict__ bias_g,  // (16,)
    float* __restrict__ yws,           // (252,250,4) padded
    float* __restrict__ cfin)          // (250,4)
{
    __shared__ float xls[16][252];  // x transposed to [b_local][t]
    const int tid = threadIdx.x;
    const int b0 = blockIdx.x * 16;

    {
        const int j = tid & 15;     // local batch
        const int t0 = tid >> 4;    // 0..3
        const bool v = (b0 + j) < 250;
        for (int t = t0; t < 250; t += 4)
            xls[j][t] = v ? x[t * 250 + b0 + j] : 0.0f;
        // pad tail (t=250,251) so tail-block register loads are defined
        if (t0 == 0) { xls[j][250] = 0.0f; xls[j][251] = 0.0f; }
    }
    __syncthreads();

    const int bl = tid >> 2;   // local batch (group of 4 lanes)
    const int u  = tid & 3;    // hidden unit owned by this lane
    const int b  = b0 + bl;
    const bool bv = b < 250;

    // Per-lane weights: rows r*4+u for r = 0(i),1(f),2(g),3(o)
    float wih[4], bb[4], whh[4][4];
#pragma unroll
    for (int r = 0; r < 4; ++r) {
        const int gr = r * 4 + u;
        wih[r] = wih_g[gr];
        bb[r]  = bias_g[gr];
#pragma unroll
        for (int j = 0; j < 4; ++j) whh[r][j] = whh_g[gr * 4 + j];
    }

    float h = 0.0f, c = 0.0f;
    float xcur = xls[bl][u];           // lane u holds x for t = 4*tb + u
    int yoff = b0 * 4 + tid;           // = t*1000 + b*4 + u at t=0

#define ENC_STEP(Q) do {                                                      \
    const float xt = qbcast<Q>(xcur);                                         \
    const float h0 = qbcast<0>(h), h1 = qbcast<1>(h);                         \
    const float h2 = qbcast<2>(h), h3 = qbcast<3>(h);                         \
    float ai = fmaf(xt, wih[0], bb[0]);                                       \
    ai = fmaf(h0, whh[0][0], ai); ai = fmaf(h1, whh[0][1], ai);               \
    ai = fmaf(h2, whh[0][2], ai); ai = fmaf(h3, whh[0][3], ai);               \
    float af = fmaf(xt, wih[1], bb[1]);                                       \
    af = fmaf(h0, whh[1][0], af); af = fmaf(h1, whh[1][1], af);               \
    af = fmaf(h2, whh[1][2], af); af = fmaf(h3, whh[1][3], af);               \
    float ag = fmaf(xt, wih[2], bb[2]);                                       \
    ag = fmaf(h0, whh[2][0], ag); ag = fmaf(h1, whh[2][1], ag);               \
    ag = fmaf(h2, whh[2][2], ag); ag = fmaf(h3, whh[2][3], ag);               \
    float ao = fmaf(xt, wih[3], bb[3]);                                       \
    ao = fmaf(h0, whh[3][0], ao); ao = fmaf(h1, whh[3][1], ao);               \
    ao = fmaf(h2, whh[3][2], ao); ao = fmaf(h3, whh[3][3], ao);               \
    const float si = sigm(ai), sf = sigm(af);                                 \
    const float tg = tanh_fast(ag), so = sigm(ao);                            \
    c = fmaf(sf, c, si * tg);                                                 \
    h = so * tanh_fast(c);                                                    \
    if (bv) yws[yoff] = h;                                                    \
    yoff += 1000;                                                             \
} while (0)

    for (int tb = 0; tb < 62; ++tb) {
        const float xnext = xls[bl][(tb + 1) * 4 + u];  // prefetch next block
        ENC_STEP(0); ENC_STEP(1); ENC_STEP(2); ENC_STEP(3);
        xcur = xnext;
    }
    // steps 248, 249
    ENC_STEP(0); ENC_STEP(1);
#undef ENC_STEP

    if (bv) cfin[b * 4 + u] = c;
}

// ---------------------------------------------------------------------------
// FC layers: one wave per output row, __shfl_xor reduce.
// ---------------------------------------------------------------------------
__global__ __launch_bounds__(256) void fc1_kernel(
    const float* __restrict__ stacked,  // (1000,)
    const float* __restrict__ w,        // (512,1000)
    const float* __restrict__ bias,     // (512,)
    float* __restrict__ out1)           // (512,)
{
    const int wave = (blockIdx.x * blockDim.x + threadIdx.x) >> 6;
    const int lane = threadIdx.x & 63;
    if (wave >= 512) return;
    const float* wr = w + wave * 1000;
    float acc = 0.0f;
    for (int n = lane; n < 1000; n += 64) acc = fmaf(stacked[n], wr[n], acc);
#pragma unroll
    for (int m = 32; m; m >>= 1) acc += __shfl_xor(acc, m, 64);
    if (lane == 0) out1[wave] = fmaxf(acc + bias[wave], 0.0f);
}

__global__ __launch_bounds__(256) void fc2_kernel(
    const float* __restrict__ v,        // (512,)
    const float* __restrict__ w,        // (250,512)
    const float* __restrict__ bias,     // (250,)
    float* __restrict__ c0dec)          // (250,)
{
    const int wave = (blockIdx.x * blockDim.x + threadIdx.x) >> 6;
    const int lane = threadIdx.x & 63;
    if (wave >= 250) return;
    const float* wr = w + wave * 512;
    float acc = 0.0f;
#pragma unroll
    for (int n = 0; n < 512; n += 64) acc = fmaf(v[n + lane], wr[n + lane], acc);
#pragma unroll
    for (int m = 32; m; m >>= 1) acc += __shfl_xor(acc, m, 64);
    if (lane == 0) c0dec[wave] = acc + bias[wave];
}

// ---------------------------------------------------------------------------
// Decoder LSTM: T=250, B=250, I=4, H=1. 4 lanes per batch element;
// lane g owns gate g (0=i,1=f,2=g,3=o). h,c replicated across the quad.
// ---------------------------------------------------------------------------
__global__ __launch_bounds__(64) void dec_kernel(
    const float* __restrict__ yws,      // (252,250,4) padded, from encoder
    const float* __restrict__ h0_dec,   // (250,1)
    const float* __restrict__ c0dec,    // (250,)
    const float* __restrict__ wih_g,    // (4,4)
    const float* __restrict__ whh_g,    // (4,1)
    const float* __restrict__ bias_g,   // (4,)
    float* __restrict__ out)            // (250,250) (t,b)
{
    const int tid = threadIdx.x;
    const int b0 = blockIdx.x * 16;
    const int bl = tid >> 2;
    const int g  = tid & 3;   // gate owned by this lane
    const int b  = b0 + bl;
    const bool bv = b < 250;
    const int bs = bv ? b : 0;  // safe index for loads

    float wih[4];
#pragma unroll
    for (int i = 0; i < 4; ++i) wih[i] = wih_g[g * 4 + i];
    const float whh = whh_g[g];
    const float bg  = bias_g[g];
    // branch-free activation select: g==2 -> tanh, else sigmoid
    const float e_scale = (g == 2) ? 2.0f : -1.0f;
    const float e_a     = (g == 2) ? -2.0f : 1.0f;
    const float e_b     = (g == 2) ? 1.0f : 0.0f;

    float h = h0_dec[bs];
    float c = c0dec[bs];

    const float4* Y = (const float4*)yws;  // Y[t*250+b] = y[t,b,0:4]
    float4 cur0 = Y[0 * 250 + bs], cur1 = Y[1 * 250 + bs];
    float4 cur2 = Y[2 * 250 + bs], cur3 = Y[3 * 250 + bs];
    int outoff = b;

#define DEC_STEP(YV) do {                                                     \
    float acc = fmaf((YV).x, wih[0], bg);                                     \
    acc = fmaf((YV).y, wih[1], acc);                                          \
    acc = fmaf((YV).z, wih[2], acc);                                          \
    acc = fmaf((YV).w, wih[3], acc);                                          \
    acc = fmaf(h, whh, acc);                                                  \
    const float r = rcp_fast(1.0f + __expf(e_scale * acc));                   \
    const float act = fmaf(e_a, r, e_b);                                      \
    const float a_i = qbcast<0>(act), a_f = qbcast<1>(act);                   \
    const float a_g = qbcast<2>(act), a_o = qbcast<3>(act);                   \
    c = fmaf(a_f, c, a_i * a_g);                                              \
    h = a_o * tanh_fast(c);                                                   \
    if (bv && g == 0) out[outoff] = h;                                        \
    outoff += 250;                                                            \
} while (0)

    for (int tb = 0; tb < 62; ++tb) {
        const int nb = (tb + 1) * 4;
        const float4 n0 = Y[(nb + 0) * 250 + bs];
        const float4 n1 = Y[(nb + 1) * 250 + bs];
        const float4 n2 = Y[(nb + 2) * 250 + bs];
        const float4 n3 = Y[(nb + 3) * 250 + bs];
        DEC_STEP(cur0); DEC_STEP(cur1); DEC_STEP(cur2); DEC_STEP(cur3);
        cur0 = n0; cur1 = n1; cur2 = n2; cur3 = n3;
    }
    // steps 248, 249
    DEC_STEP(cur0); DEC_STEP(cur1);
#undef DEC_STEP
}

extern "C" void kernel_launch(void* const* d_in, const int* in_sizes, int n_in,
                              void* d_out, int out_size, void* d_ws, size_t ws_size,
                              hipStream_t stream) {
    const float* x        = (const float*)d_in[0];
    const float* h0_dec   = (const float*)d_in[1];
    const float* enc_w_ih = (const float*)d_in[2];
    const float* enc_w_hh = (const float*)d_in[3];
    const float* enc_b    = (const float*)d_in[4];
    const float* fc1_w    = (const float*)d_in[5];
    const float* fc1_b    = (const float*)d_in[6];
    const float* fc2_w    = (const float*)d_in[7];
    const float* fc2_b    = (const float*)d_in[8];
    const float* dec_w_ih = (const float*)d_in[9];
    const float* dec_w_hh = (const float*)d_in[10];
    const float* dec_b    = (const float*)d_in[11];
    float* out = (float*)d_out;

    float* ws    = (float*)d_ws;
    float* yws   = ws;              // 252*1000 = 252000 floats (padded)
    float* cfin  = ws + 252000;     // 1000
    float* out1  = ws + 253000;     // 512
    float* c0dec = ws + 253512;     // 250

    enc_kernel<<<dim3(16), dim3(64), 0, stream>>>(x, enc_w_ih, enc_w_hh, enc_b,
                                                  yws, cfin);
    fc1_kernel<<<dim3(128), dim3(256), 0, stream>>>(cfin, fc1_w, fc1_b, out1);
    fc2_kernel<<<dim3(63), dim3(256), 0, stream>>>(out1, fc2_w, fc2_b, c0dec);
    dec_kernel<<<dim3(16), dim3(64), 0, stream>>>(yws, h0_dec, c0dec,
                                                  dec_w_ih, dec_w_hh, dec_b, out);
}

// Round 2
// 66.119 us; speedup vs baseline: 1.3504x; 1.3504x over previous
//
#include <hip/hip_runtime.h>

#define DEVINL __device__ __forceinline__

typedef float f2 __attribute__((ext_vector_type(2)));

DEVINL float rcp_fast(float x) { return __builtin_amdgcn_rcpf(x); }

#if __has_builtin(__builtin_amdgcn_exp2f)
DEVINL float exp2_fast(float x) { return __builtin_amdgcn_exp2f(x); }
#else
DEVINL float exp2_fast(float x) { return exp2f(x); }
#endif

// Broadcast lane L (0..3) of each 4-lane quad to all 4 lanes (DPP quad_perm).
template <int L>
DEVINL float qbcast(float v) {
    return __int_as_float(__builtin_amdgcn_update_dpp(
        0, __float_as_int(v), L * 0x55, 0xF, 0xF, true));
}

DEVINL f2 splat2(float s) { f2 r; r.x = s; r.y = s; return r; }

constexpr float L2E = 1.4426950408889634f;   // log2(e)
constexpr float K2  = 2.8853900817779268f;   // 2*log2(e)

// ---------------------------------------------------------------------------
// Encoder LSTM: T=250, B=250, I=1, H=4. 4 lanes per batch element; lane u owns
// hidden unit u. Weights pre-scaled by -log2e (sigmoid rows) / +2log2e (tanh
// row) so activations feed v_exp_f32 (exp2) directly. Gate pairs (i,f),(g,o)
// packed as float2 -> v_pk_fma_f32. Unconditional per-step stores via per-lane
// pointer (+dump for inactive lanes). x prefetched 2 blocks (8 steps) ahead.
// ---------------------------------------------------------------------------
__global__ __launch_bounds__(64) void enc_kernel(
    const float* __restrict__ x,      // (250,250) (t,b)
    const float* __restrict__ wih,    // (16,1)
    const float* __restrict__ whh,    // (16,4)
    const float* __restrict__ bias,   // (16,)
    float* __restrict__ yws,          // (250,250,4)
    float* __restrict__ cfin,         // (250,4)
    float* __restrict__ dump)         // scratch, never read
{
    const int tid = threadIdx.x;
    const int b0 = blockIdx.x * 16;
    const int bl = tid >> 2;
    const int u  = tid & 3;
    const int b  = b0 + bl;
    const bool bv = b < 250;
    const int bs = bv ? b : 0;

    // Gate rows: i=u, f=4+u, g=8+u, o=12+u. Pre-scale: sigmoid rows by -log2e,
    // tanh(g) row by +2log2e, so  sig(a)=rcp(1+exp2(acc)), tanh(a)=1-2*rcp(1+exp2(acc)).
    const float sI = -L2E, sF = -L2E, sG = 2.0f * L2E, sO = -L2E;
    f2 wihA, wihB, bbA, bbB, whhA[4], whhB[4];
    wihA.x = wih[u]      * sI;  wihA.y = wih[4 + u]  * sF;
    wihB.x = wih[8 + u]  * sG;  wihB.y = wih[12 + u] * sO;
    bbA.x  = bias[u]     * sI;  bbA.y  = bias[4 + u] * sF;
    bbB.x  = bias[8 + u] * sG;  bbB.y  = bias[12 + u]* sO;
#pragma unroll
    for (int j = 0; j < 4; ++j) {
        whhA[j].x = whh[u * 4 + j]        * sI;
        whhA[j].y = whh[(4 + u) * 4 + j]  * sF;
        whhB[j].x = whh[(8 + u) * 4 + j]  * sG;
        whhB[j].y = whh[(12 + u) * 4 + j] * sO;
    }

    float h = 0.0f, c = 0.0f;

    // lane u of each quad holds x[(4*tb+u)][bs]; two 4-step blocks in flight
    float xA = x[(0 + u) * 250 + bs];
    float xB = x[(4 + u) * 250 + bs];

    float* yp = bv ? (yws + b * 4 + u) : (dump + blockIdx.x * 64 + tid);
    const int yinc = bv ? 1000 : 0;

#define ENC_STEP(XR, Q) do {                                                  \
    const float xt = qbcast<Q>(XR);                                           \
    const float h0 = qbcast<0>(h), h1 = qbcast<1>(h);                         \
    const float h2 = qbcast<2>(h), h3 = qbcast<3>(h);                         \
    f2 aA = splat2(xt) * wihA + bbA;                                          \
    f2 aB = splat2(xt) * wihB + bbB;                                          \
    f2 tA = splat2(h1) * whhA[1] + (splat2(h0) * whhA[0] + aA);               \
    f2 uA = splat2(h3) * whhA[3] + (splat2(h2) * whhA[2]);                    \
    f2 tB = splat2(h1) * whhB[1] + (splat2(h0) * whhB[0] + aB);               \
    f2 uB = splat2(h3) * whhB[3] + (splat2(h2) * whhB[2]);                    \
    const f2 accA = tA + uA;                                                  \
    const f2 accB = tB + uB;                                                  \
    const float ri = rcp_fast(1.0f + exp2_fast(accA.x));                      \
    const float rf = rcp_fast(1.0f + exp2_fast(accA.y));                      \
    const float rg = rcp_fast(1.0f + exp2_fast(accB.x));                      \
    const float ro = rcp_fast(1.0f + exp2_fast(accB.y));                      \
    const float tg = fmaf(-2.0f, rg, 1.0f);                                   \
    c = fmaf(ri, tg, rf * c);                                                 \
    const float n2so = -2.0f * ro;                                            \
    const float r2 = rcp_fast(1.0f + exp2_fast(c * K2));                      \
    h = fmaf(n2so, r2, ro);                                                   \
    *yp = h; yp += yinc;                                                      \
} while (0)

    for (int tb = 0; tb < 62; ++tb) {
        const int tn = (tb + 2) * 4 + u;
        const float xC = x[min(tn, 249) * 250 + bs];  // prefetch 2 blocks ahead
        ENC_STEP(xA, 0); ENC_STEP(xA, 1); ENC_STEP(xA, 2); ENC_STEP(xA, 3);
        xA = xB; xB = xC;
    }
    // steps 248, 249 (xA = t-block 62)
    ENC_STEP(xA, 0); ENC_STEP(xA, 1);
#undef ENC_STEP

    if (bv) cfin[b * 4 + u] = c;
}

// ---------------------------------------------------------------------------
// FC layers: one wave per output row, __shfl_xor reduce.
// ---------------------------------------------------------------------------
__global__ __launch_bounds__(256) void fc1_kernel(
    const float* __restrict__ stacked,  // (1000,)
    const float* __restrict__ w,        // (512,1000)
    const float* __restrict__ bias,     // (512,)
    float* __restrict__ out1)           // (512,)
{
    const int wave = (blockIdx.x * blockDim.x + threadIdx.x) >> 6;
    const int lane = threadIdx.x & 63;
    if (wave >= 512) return;
    const float* wr = w + wave * 1000;
    float acc = 0.0f;
    for (int n = lane; n < 1000; n += 64) acc = fmaf(stacked[n], wr[n], acc);
#pragma unroll
    for (int m = 32; m; m >>= 1) acc += __shfl_xor(acc, m, 64);
    if (lane == 0) out1[wave] = fmaxf(acc + bias[wave], 0.0f);
}

__global__ __launch_bounds__(256) void fc2_kernel(
    const float* __restrict__ v,        // (512,)
    const float* __restrict__ w,        // (250,512)
    const float* __restrict__ bias,     // (250,)
    float* __restrict__ c0dec)          // (250,)
{
    const int wave = (blockIdx.x * blockDim.x + threadIdx.x) >> 6;
    const int lane = threadIdx.x & 63;
    if (wave >= 250) return;
    const float* wr = w + wave * 512;
    float acc = 0.0f;
#pragma unroll
    for (int n = 0; n < 512; n += 64) acc = fmaf(v[n + lane], wr[n + lane], acc);
#pragma unroll
    for (int m = 32; m; m >>= 1) acc += __shfl_xor(acc, m, 64);
    if (lane == 0) c0dec[wave] = acc + bias[wave];
}

// ---------------------------------------------------------------------------
// Decoder LSTM: T=250, B=250, I=4, H=1. 4 lanes per batch element; lane g owns
// gate g (0=i,1=f,2=g,3=o); h,c replicated across the quad. Weights pre-scaled
// per-gate so the activation is rcp(1+exp2(acc)) directly. y prefetched
// 2 blocks (8 steps) ahead as float4. Unconditional per-step stores.
// ---------------------------------------------------------------------------
__global__ __launch_bounds__(64) void dec_kernel(
    const float* __restrict__ yws,      // (250,250,4)
    const float* __restrict__ h0_dec,   // (250,)
    const float* __restrict__ c0dec,    // (250,)
    const float* __restrict__ wih,      // (4,4)
    const float* __restrict__ whh,      // (4,1)
    const float* __restrict__ bias,     // (4,)
    float* __restrict__ out,            // (250,250) (t,b)
    float* __restrict__ dump)           // scratch, never read
{
    const int tid = threadIdx.x;
    const int b0 = blockIdx.x * 16;
    const int bl = tid >> 2;
    const int g  = tid & 3;
    const int b  = b0 + bl;
    const bool bv = b < 250;
    const int bs = bv ? b : 0;

    const float sg = (g == 2) ? 2.0f * L2E : -L2E;
    const float w0 = wih[g * 4 + 0] * sg, w1 = wih[g * 4 + 1] * sg;
    const float w2 = wih[g * 4 + 2] * sg, w3 = wih[g * 4 + 3] * sg;
    const float wh = whh[g] * sg;
    const float bg = bias[g] * sg;
    const float e_a = (g == 2) ? -2.0f : 1.0f;   // act = e_a*r + e_b
    const float e_b = (g == 2) ? 1.0f : 0.0f;

    float h = h0_dec[bs];
    float c = c0dec[bs];

    const float4* Y = (const float4*)yws;  // Y[t*250+b] = y[t,b,0:4]
    float4 A0 = Y[0 * 250 + bs], A1 = Y[1 * 250 + bs];
    float4 A2 = Y[2 * 250 + bs], A3 = Y[3 * 250 + bs];
    float4 B0 = Y[4 * 250 + bs], B1 = Y[5 * 250 + bs];
    float4 B2 = Y[6 * 250 + bs], B3 = Y[7 * 250 + bs];

    float* op = (bv && g == 0) ? (out + b) : (dump + blockIdx.x * 64 + tid);
    const int oinc = (bv && g == 0) ? 250 : 0;

#define DEC_STEP(YV) do {                                                     \
    const float base = fmaf((YV).w, w3, fmaf((YV).z, w2,                      \
                       fmaf((YV).y, w1, fmaf((YV).x, w0, bg))));              \
    const float acc = fmaf(h, wh, base);                                      \
    const float r = rcp_fast(1.0f + exp2_fast(acc));                          \
    const float act = fmaf(e_a, r, e_b);                                      \
    const float ai = qbcast<0>(act), af = qbcast<1>(act);                     \
    const float ag = qbcast<2>(act), ao = qbcast<3>(act);                     \
    c = fmaf(af, c, ai * ag);                                                 \
    const float n2ao = -2.0f * ao;                                            \
    const float r2 = rcp_fast(1.0f + exp2_fast(c * K2));                      \
    h = fmaf(n2ao, r2, ao);                                                   \
    *op = h; op += oinc;                                                      \
} while (0)

    for (int tb = 0; tb < 62; ++tb) {
        const int nb = (tb + 2) * 4;  // prefetch 2 blocks ahead (clamped)
        const float4 C0 = Y[min(nb + 0, 249) * 250 + bs];
        const float4 C1 = Y[min(nb + 1, 249) * 250 + bs];
        const float4 C2 = Y[min(nb + 2, 249) * 250 + bs];
        const float4 C3 = Y[min(nb + 3, 249) * 250 + bs];
        DEC_STEP(A0); DEC_STEP(A1); DEC_STEP(A2); DEC_STEP(A3);
        A0 = B0; A1 = B1; A2 = B2; A3 = B3;
        B0 = C0; B1 = C1; B2 = C2; B3 = C3;
    }
    // steps 248, 249
    DEC_STEP(A0); DEC_STEP(A1);
#undef DEC_STEP
}

extern "C" void kernel_launch(void* const* d_in, const int* in_sizes, int n_in,
                              void* d_out, int out_size, void* d_ws, size_t ws_size,
                              hipStream_t stream) {
    const float* x        = (const float*)d_in[0];
    const float* h0_dec   = (const float*)d_in[1];
    const float* enc_w_ih = (const float*)d_in[2];
    const float* enc_w_hh = (const float*)d_in[3];
    const float* enc_b    = (const float*)d_in[4];
    const float* fc1_w    = (const float*)d_in[5];
    const float* fc1_b    = (const float*)d_in[6];
    const float* fc2_w    = (const float*)d_in[7];
    const float* fc2_b    = (const float*)d_in[8];
    const float* dec_w_ih = (const float*)d_in[9];
    const float* dec_w_hh = (const float*)d_in[10];
    const float* dec_b    = (const float*)d_in[11];
    float* out = (float*)d_out;

    float* ws      = (float*)d_ws;
    float* yws     = ws;             // 250*250*4 = 250000 floats
    float* cfin    = ws + 250000;    // 1000
    float* out1    = ws + 251008;    // 512
    float* c0dec   = ws + 251520;    // 250
    float* encdump = ws + 251776;    // 1024
    float* decdump = ws + 252800;    // 1024

    enc_kernel<<<dim3(16), dim3(64), 0, stream>>>(x, enc_w_ih, enc_w_hh, enc_b,
                                                  yws, cfin, encdump);
    fc1_kernel<<<dim3(128), dim3(256), 0, stream>>>(cfin, fc1_w, fc1_b, out1);
    fc2_kernel<<<dim3(63), dim3(256), 0, stream>>>(out1, fc2_w, fc2_b, c0dec);
    dec_kernel<<<dim3(16), dim3(64), 0, stream>>>(yws, h0_dec, c0dec,
                                                  dec_w_ih, dec_w_hh, dec_b,
                                                  out, decdump);
}